// Round 15
// baseline (91.831 us; speedup 1.0000x reference)
//
#include <hip/hip_runtime.h>
#include <cstdint>

#define B_ 2
#define E_ 16
#define H_ 160
#define W_ 288
#define N_ 12
#define T_ 2
#define HW_ (H_*W_)        // 46080
#define P_ (T_*HW_)        // 92160
#define NINST (B_*N_)      // 24
#define NBINS 128          // err in [0,2] -> bin = min(127, err*64)
#define BINSCALE 64.0f
#define CHUNK 1536         // px per block; 30 chunks/frame, 60/instance
#define NCHUNK 60
#define NGROUPS 120        // (b,chunk) groups: 2 * 60
#define GRID_SWZ 1440      // 8 xcd * 15 gslots * 12 instances (bijective, no padding)
#define PSTRIDE 36         // partial-slot stride (33 floats used)

typedef unsigned long long u64;
typedef unsigned int u32;

__device__ inline float waveReduceSum(float v){
  #pragma unroll
  for(int o=32;o>0;o>>=1) v += __shfl_down(v, o, 64);
  return v;
}

// Fold-reduction: sum v[0..15] across 64 lanes in 15+2 shuffles.
// Result: every lane holds the 64-lane sum of e = bitrev4(lane&15).
#define FOLD_STEP(m, half) \
  { bool hi = (lane & (m)) != 0; \
    _Pragma("unroll") \
    for(int i=0;i<(half);i++){ \
      float send = hi ? v[i] : v[i+(half)]; \
      float recv = __shfl_xor(send, (m), 64); \
      v[i] = (hi ? v[i+(half)] : v[i]) + recv; } }

__device__ inline float fold16sum(float* v, int lane){
  FOLD_STEP(1,8) FOLD_STEP(2,4) FOLD_STEP(4,2) FOLD_STEP(8,1)
  float r = v[0];
  r += __shfl_xor(r, 16, 64);
  r += __shfl_xor(r, 32, 64);
  return r;
}

// XCD swizzle: the 12 instance-blocks sharing one (b,chunk) emb tile are
// congruent mod 8 -> same XCD L2 (and k_err re-reads hit L2 from k_stats).
// 120 groups / 8 xcd = 15 gslots exactly -> bijective, no padding blocks.
__device__ inline void decode_blk(int lid, int& bn, int& t, int& rbase, int& y_out){
  int xcd = lid & 7, k = lid >> 3;
  int j = k % 12, gslot = k / 12;       // gslot 0..14
  int g = xcd + 8*gslot;                // 0..119
  int b = g & 1, y = g >> 1;            // y = chunk 0..59
  bn = b*N_ + j;
  t = y / 30;
  rbase = (y - t*30) * CHUNK;
  y_out = y;
}

// ---- Pass A: masked sum + sum-of-squares + count -> per-block partial slot
// (non-atomic, fully overwritten -> no pre-zero). Also zeroes hist/esum/out.
// iter-B float2 loads PRELOADED before iter-A compute: removes the second
// HBM-latency exposure per block. +32 VGPR (~52->~85) keeps 6 blocks/CU
// co-residency (2048/85 ~ 24 waves/CU >= 5.625x4 needed).
__global__ __launch_bounds__(256) void k_stats(const float* __restrict__ mf1,
                        const float* __restrict__ mf2,
                        const int* __restrict__ gt,
                        float* __restrict__ partial,
                        u64* __restrict__ hist, float* __restrict__ esum,
                        float* __restrict__ out){
  int lid = blockIdx.x, tid = threadIdx.x;
  int gtid = lid*256 + tid;
  if(gtid < NINST*NBINS){ hist[gtid] = 0ull; esum[gtid] = 0.f; }
  if(gtid == 0) *out = 0.f;

  int bn, t, rbase, y;
  decode_blk(lid, bn, t, rbase, y);
  int b = bn / N_;
  int lane = tid & 63;

  const float* ep = (t ? mf2 : mf1) + (size_t)b*(E_*HW_);
  const int*   gp = gt + ((size_t)bn*T_ + t)*HW_ + rbase;

  // issue masks + ALL iter-B loads up front (independent, stay in flight)
  int4 m4 = *(const int4*)(gp + tid*4);
  int2 mm = *(const int2*)(gp + 1024 + tid*2);
  float2 xb[E_];
  #pragma unroll
  for(int e=0;e<E_;e++)
    xb[e] = *(const float2*)(ep + (size_t)e*HW_ + rbase + 1024 + tid*2);

  float s[E_], q[E_]; float c;
  { // iter A: px [0,1024)
    int off = tid*4;
    float m0=(float)m4.x, m1=(float)m4.y, m2=(float)m4.z, m3=(float)m4.w;
    c = m0+m1+m2+m3;
    #pragma unroll
    for(int e=0;e<E_;e++){
      float4 x = *(const float4*)(ep + (size_t)e*HW_ + rbase + off);
      float mx0=m0*x.x; float se=mx0;       float qe=mx0*x.x;
      float mx1=m1*x.y; se+=mx1; qe=fmaf(mx1,x.y,qe);
      float mx2=m2*x.z; se+=mx2; qe=fmaf(mx2,x.z,qe);
      float mx3=m3*x.w; se+=mx3; qe=fmaf(mx3,x.w,qe);
      s[e]=se; q[e]=qe;
    }
  }
  { // iter B: px [1024,1536) -- consumes preloaded xb
    float m0=(float)mm.x, m1=(float)mm.y;
    c += m0+m1;
    #pragma unroll
    for(int e=0;e<E_;e++){
      float2 x = xb[e];
      float se=s[e], qe=q[e];
      float mx0=m0*x.x; se+=mx0; qe=fmaf(mx0,x.x,qe);
      float mx1=m1*x.y; se+=mx1; qe=fmaf(mx1,x.y,qe);
      s[e]=se; q[e]=qe;
    }
  }

  __shared__ float red[2*E_+1];
  if(tid < 2*E_+1) red[tid] = 0.f;
  __syncthreads();
  float sf = fold16sum(s, lane);
  float qf = fold16sum(q, lane);
  float cf = waveReduceSum(c);
  int ee = ((lane&1)<<3)|((lane&2)<<1)|((lane&4)>>1)|((lane&8)>>3);  // bitrev4
  if(lane < 16){
    atomicAdd(&red[ee],    sf);
    atomicAdd(&red[E_+ee], qf);
  }
  if(lane == 0) atomicAdd(&red[2*E_], cf);
  __syncthreads();
  if(tid < 2*E_+1) partial[(bn*NCHUNK + y)*PSTRIDE + tid] = red[tid];
}

// ---- Pass B: per-instance LDS histogram of (count, labelsum, errsum).
// mean/var recomputed per block from partials (4 segs x 15 independent loads;
// fixed combine order -> bit-identical across blocks of an instance).
// gt re-read directly (L2-hot under the XCD swizzle). Bins 0 / NBINS-1
// (~50% of px) accumulate in registers -> no LDS-atomic hotspots.
__global__ __launch_bounds__(256) void k_err(const float* __restrict__ mf1,
                                             const float* __restrict__ mf2,
                                             const int* __restrict__ gt,
                                             const float* __restrict__ partial,
                                             u64* __restrict__ hist,
                                             float* __restrict__ esum){
  __shared__ u32   hcl[NBINS];   // count<<16 | labelsum (block-local, fits 16b)
  __shared__ float hes[NBINS];
  __shared__ float red[2*E_+1];
  __shared__ float pred[4][2*E_+1];
  int bn, t, rbase, y;
  decode_blk(blockIdx.x, bn, t, rbase, y);
  int tid = threadIdx.x, lane = tid & 63, wave = tid >> 6;
  int b = bn / N_;

  // stage 1: segment sums (4 segs x 15 chunks); loads independent
  {
    int seg = wave, val = lane;
    if(val < 2*E_+1){
      float v = 0.f;
      #pragma unroll
      for(int i=0;i<15;i++)
        v += partial[(bn*NCHUNK + seg*15 + i)*PSTRIDE + val];
      pred[seg][val] = v;
    }
  }
  if(tid < NBINS){ hcl[tid]=0u; hes[tid]=0.f; }
  __syncthreads();
  // stage 2: fixed-order combine -> bit-identical across blocks of same bn
  if(tid < 2*E_+1)
    red[tid] = ((pred[0][tid] + pred[1][tid]) + pred[2][tid]) + pred[3][tid];
  __syncthreads();
  if(tid < E_){
    float cc = red[2*E_];
    float mu = red[tid] / cc;
    float vv = (red[E_+tid] - cc*mu*mu) / (cc - 1.0f);
    red[tid] = mu; red[E_+tid] = vv;   // thread e only touches e, 16+e
  }
  __syncthreads();
  float mn[E_], sv[E_];
  #pragma unroll
  for(int e=0;e<E_;e++){ mn[e]=red[e]; sv[e]=red[E_+e]; }

  const float* ep = (t ? mf2 : mf1) + (size_t)b*(E_*HW_);
  const int*   gp = gt + ((size_t)bn*T_ + t)*HW_ + rbase;

  float h0c=0.f,h0l=0.f,h0e=0.f, h1c=0.f,h1l=0.f,h1e=0.f;
  auto proc = [&](float d, int mi){
    float logits = 2.f*__expf(-0.5f*d) - 1.f;
    float ev = fmaxf(1.f - logits*(2.f*(float)mi - 1.f), 0.f);   // in [0,2]
    int bin = min(NBINS-1, (int)(ev * BINSCALE));
    if(bin == 0)            { h0c+=1.f; h0l+=(float)mi; h0e+=ev; }
    else if(bin == NBINS-1) { h1c+=1.f; h1l+=(float)mi; h1e+=ev; }
    else {
      atomicAdd(&hcl[bin], 0x10000u | (u32)mi);
      atomicAdd(&hes[bin], ev);
    }
  };

  { // iter A: px [0,1024)
    int off = tid*4;
    int4 m4 = *(const int4*)(gp + off);
    float d0=0.f,d1=0.f,d2=0.f,d3=0.f;
    #pragma unroll
    for(int e=0;e<E_;e++){
      float4 x = *(const float4*)(ep + (size_t)e*HW_ + rbase + off);
      float mne=mn[e], sve=sv[e];
      float f0=x.x-mne; d0=fmaf(f0*f0, sve, d0);
      float f1=x.y-mne; d1=fmaf(f1*f1, sve, d1);
      float f2=x.z-mne; d2=fmaf(f2*f2, sve, d2);
      float f3=x.w-mne; d3=fmaf(f3*f3, sve, d3);
    }
    proc(d0,m4.x); proc(d1,m4.y); proc(d2,m4.z); proc(d3,m4.w);
  }
  { // iter B: px [1024,1536)
    int off = 1024 + tid*2;
    int2 mm = *(const int2*)(gp + off);
    float d0=0.f,d1=0.f;
    #pragma unroll
    for(int e=0;e<E_;e++){
      float2 x = *(const float2*)(ep + (size_t)e*HW_ + rbase + off);
      float mne=mn[e], sve=sv[e];
      float f0=x.x-mne; d0=fmaf(f0*f0, sve, d0);
      float f1=x.y-mne; d1=fmaf(f1*f1, sve, d1);
    }
    proc(d0,mm.x); proc(d1,mm.y);
  }

  // flush hot-bin registers (one wave-reduce, 4 LDS atomics per wave)
  h0c = waveReduceSum(h0c); h0l = waveReduceSum(h0l); h0e = waveReduceSum(h0e);
  h1c = waveReduceSum(h1c); h1l = waveReduceSum(h1l); h1e = waveReduceSum(h1e);
  if(lane == 0){
    if(h0c > 0.f){ atomicAdd(&hcl[0],       (((u32)h0c)<<16) | (u32)h0l); atomicAdd(&hes[0],       h0e); }
    if(h1c > 0.f){ atomicAdd(&hcl[NBINS-1], (((u32)h1c)<<16) | (u32)h1l); atomicAdd(&hes[NBINS-1], h1e); }
  }
  __syncthreads();

  u64*   hp = hist + (size_t)bn*NBINS;
  float* sp = esum + (size_t)bn*NBINS;
  if(tid < NBINS){
    u32 v = hcl[tid];
    if(v){
      atomicAdd(&hp[tid], ((u64)(v>>16)<<32) | (u64)(v & 0xffffu));
      atomicAdd(&sp[tid], hes[tid]);
    }
  }
}

// ---- Pass C: per-instance descending bin scan + closed-form lovasz dot.
__global__ __launch_bounds__(256) void k_bins(const u64* __restrict__ hist,
                                              const float* __restrict__ esum,
                                              const float* __restrict__ partial,
                                              float* __restrict__ out){
  int bn = blockIdx.x;
  const u64*   h  = hist + (size_t)bn*NBINS;
  const float* es = esum + (size_t)bn*NBINS;
  int tid = threadIdx.x, lane = tid & 63, wave = tid >> 6;

  __shared__ float Gs;
  // parallel G: counts are integer-valued floats -> any sum order is exact
  if(wave == 0){
    float gv = (lane < NCHUNK) ? partial[(bn*NCHUNK + lane)*PSTRIDE + 2*E_] : 0.f;
    gv = waveReduceSum(gv);
    if(lane == 0) Gs = gv;
  }

  // 1 bin per thread (reversed order); threads >= NBINS carry zero
  u64 s = (tid < NBINS) ? h[NBINS-1 - tid] : 0ull;
  u64 sc = s;
  #pragma unroll
  for(int off=1;off<64;off<<=1){ u64 v = __shfl_up(sc, off, 64); if(lane>=off) sc += v; }
  __shared__ u64 wsum[4], wbase[4];
  if(lane==63) wsum[wave] = sc;
  __syncthreads();
  if(tid==0){
    u64 run = 0;
    #pragma unroll
    for(int w=0;w<4;w++){ wbase[w] = run; run += wsum[w]; }
  }
  __syncthreads();
  u64 excl = wbase[wave] + (sc - s);

  float G = Gs;
  float lsum = 0.f;
  {
    u64 lv = s;
    u32 cb = (u32)(lv>>32), lb = (u32)(lv & 0xffffffffu);
    if(cb){
      float i0 = (float)(u32)(excl>>32);
      float c0 = (float)(u32)(excl & 0xffffffffu);
      float c1 = c0 + (float)lb;
      float jend   = 1.f - (G - c1)/(G + i0 + (float)cb - c1);
      float jstart = 1.f - (G - c0)/(G + i0 - c0);   // i0=0,c0=0 -> 0
      lsum = (es[NBINS-1 - tid] / (float)cb) * (jend - jstart);
    }
  }

  __shared__ float rs[4];
  float tot = waveReduceSum(lsum);
  if(lane==0) rs[wave] = tot;
  __syncthreads();
  if(tid==0) atomicAdd(out, (rs[0]+rs[1]+rs[2]+rs[3]) * (1.0f/(float)NINST));
}

extern "C" void kernel_launch(void* const* d_in, const int* in_sizes, int n_in,
                              void* d_out, int out_size, void* d_ws, size_t ws_size,
                              hipStream_t stream){
  const float* mf1 = (const float*)d_in[0];
  const float* mf2 = (const float*)d_in[1];
  const int*   gt  = (const int*)d_in[2];
  float* out = (float*)d_out;

  // ws layout
  u64*   hist    = (u64*)d_ws;                                      // 24*128*8 = 24 KB
  float* esum    = (float*)((char*)d_ws + 24576);                   // 12 KB
  float* partial = (float*)((char*)d_ws + 36864);                   // 203 KB

  k_stats<<<GRID_SWZ, 256, 0, stream>>>(mf1, mf2, gt, partial, hist, esum, out);
  k_err  <<<GRID_SWZ, 256, 0, stream>>>(mf1, mf2, gt, partial, hist, esum);
  k_bins <<<NINST, 256, 0, stream>>>(hist, esum, partial, out);
}